// Round 5
// baseline (437.935 us; speedup 1.0000x reference)
//
#include <hip/hip_runtime.h>
#include <hip/hip_fp16.h>

#define NKr 65536   // N*K positions per batch
#define LOG2E 1.44269504f

typedef __attribute__((ext_vector_type(4))) float f32x4;
typedef __attribute__((ext_vector_type(8))) short s16x8;

// fp32 -> bf16 (RNE)
__device__ __forceinline__ short bfc(float x){
    union{float f; unsigned u;} a; a.f = x;
    unsigned r = a.u + 0x7fffu + ((a.u >> 16) & 1u);
    return (short)(r >> 16);
}
__device__ __forceinline__ short hfc(float x){
    __half h = __float2half(x);
    return *(short*)&h;
}
__device__ __forceinline__ float hdec(unsigned short s){
    __half h = *(__half*)&s;
    return __half2float(h);
}

// ---------------------------------------------------------------------------
// K0: convert weights to bf16. wbf layout (halves): pm1p@0 [64][32] zero-pad,
// pb1p@2048, then 64x64: pm2@4096, pb2@8192, kW@12288, vW@16384, we1@20480,
// we2@24576, resW@28672.  Parallel: 64 blocks.
// ---------------------------------------------------------------------------
__global__ void k0_kernel(const float* __restrict__ pm1W, const float* __restrict__ pb1W,
                          const float* __restrict__ pm2W, const float* __restrict__ pb2W,
                          const float* __restrict__ kW,   const float* __restrict__ vW,
                          const float* __restrict__ we1W, const float* __restrict__ we2W,
                          const float* __restrict__ resW, short* __restrict__ wbf)
{
    const int tg = blockIdx.x * 256 + threadIdx.x;
    for (int i = tg; i < 32768; i += 16384){
        short v;
        if (i < 2048){
            const int o = i >> 5, c = i & 31;
            v = (c < 3) ? bfc(pm1W[o*3 + c]) : (short)0;
        } else if (i < 4096){
            const int ii = i - 2048, o = ii >> 5, c = ii & 31;
            v = (c < 3) ? bfc(pb1W[o*3 + c]) : (short)0;
        } else {
            const int m = (i - 4096) >> 12, j = (i - 4096) & 4095;
            const float* s = (m == 0) ? pm2W : (m == 1) ? pb2W : (m == 2) ? kW
                           : (m == 3) ? vW   : (m == 4) ? we1W : (m == 5) ? we2W : resW;
            v = bfc(s[j]);
        }
        wbf[i] = v;
    }
}

// ---------------------------------------------------------------------------
// MFMA helpers. Tile layout: position-major [p][64c] bf16/fp16, 128B rows,
// XOR-swizzled: half_idx = (p*64 + c) ^ ((p&7)<<3)  (16B-granule swizzle).
// MFMA mapping (16x16x32 bf16): A lane: m=li, k=hi*8+j ; B lane: k=hi*8+j,
// n=li ; D lane: row=o=16mi+4hi+j, col=p=16ni+li  (li=l&15, hi=l>>4).
// ---------------------------------------------------------------------------
__device__ __forceinline__ void gemm64(const short* __restrict__ S,
                                       const short* __restrict__ wbf, int wo,
                                       const float* __restrict__ bias,
                                       int li, int hi, f32x4 acc[4][4])
{
#pragma unroll
    for (int mi = 0; mi < 4; ++mi){
        const float4 bv = *(const float4*)(bias + 16*mi + 4*hi);
#pragma unroll
        for (int ni = 0; ni < 4; ++ni){
            acc[mi][ni][0] = bv.x; acc[mi][ni][1] = bv.y;
            acc[mi][ni][2] = bv.z; acc[mi][ni][3] = bv.w;
        }
    }
#pragma unroll
    for (int ks = 0; ks < 2; ++ks){
        s16x8 af[4];
#pragma unroll
        for (int mi = 0; mi < 4; ++mi)
            af[mi] = *(const s16x8*)(wbf + wo + (16*mi + li)*64 + ks*32 + hi*8);
#pragma unroll
        for (int ni = 0; ni < 4; ++ni){
            const int p = 16*ni + li;
            const s16x8 bf_ = *(const s16x8*)(S + ((p*64 + ks*32 + hi*8) ^ ((li & 7) << 3)));
#pragma unroll
            for (int mi = 0; mi < 4; ++mi)
                acc[mi][ni] = __builtin_amdgcn_mfma_f32_16x16x32_bf16(af[mi], bf_, acc[mi][ni], 0, 0, 0);
        }
    }
}

// K=32 GEMM with B-frags in registers (xyz, padded K 3->32)
__device__ __forceinline__ void gemm32x(const s16x8* __restrict__ xf,
                                        const short* __restrict__ wbf, int wo,
                                        const float* __restrict__ bias,
                                        int li, int hi, f32x4 acc[4][4])
{
#pragma unroll
    for (int mi = 0; mi < 4; ++mi){
        const float4 bv = *(const float4*)(bias + 16*mi + 4*hi);
#pragma unroll
        for (int ni = 0; ni < 4; ++ni){
            acc[mi][ni][0] = bv.x; acc[mi][ni][1] = bv.y;
            acc[mi][ni][2] = bv.z; acc[mi][ni][3] = bv.w;
        }
    }
    s16x8 af[4];
#pragma unroll
    for (int mi = 0; mi < 4; ++mi)
        af[mi] = *(const s16x8*)(wbf + wo + (16*mi + li)*32 + hi*8);
#pragma unroll
    for (int ni = 0; ni < 4; ++ni)
#pragma unroll
        for (int mi = 0; mi < 4; ++mi)
            acc[mi][ni] = __builtin_amdgcn_mfma_f32_16x16x32_bf16(af[mi], xf[ni], acc[mi][ni], 0, 0, 0);
}

// D-frags -> swizzled LDS tile, bf16 (optional relu)
__device__ __forceinline__ void dstore_bf(short* __restrict__ Tt, f32x4 acc[4][4],
                                          int li, int hi, bool relu)
{
#pragma unroll
    for (int mi = 0; mi < 4; ++mi){
        const int o0 = 16*mi + 4*hi;
#pragma unroll
        for (int ni = 0; ni < 4; ++ni){
            const int p = 16*ni + li;
            float a0 = acc[mi][ni][0], a1 = acc[mi][ni][1];
            float a2 = acc[mi][ni][2], a3 = acc[mi][ni][3];
            if (relu){ a0 = fmaxf(a0, 0.f); a1 = fmaxf(a1, 0.f);
                       a2 = fmaxf(a2, 0.f); a3 = fmaxf(a3, 0.f); }
            uint2 pk;
            pk.x = (unsigned)(unsigned short)bfc(a0) | ((unsigned)(unsigned short)bfc(a1) << 16);
            pk.y = (unsigned)(unsigned short)bfc(a2) | ((unsigned)(unsigned short)bfc(a3) << 16);
            *(uint2*)(Tt + ((p*64 + o0) ^ ((li & 7) << 3))) = pk;
        }
    }
}

// D-frags -> swizzled LDS tile, fp16
__device__ __forceinline__ void dstore_h16(short* __restrict__ Tt, f32x4 acc[4][4],
                                           int li, int hi)
{
#pragma unroll
    for (int mi = 0; mi < 4; ++mi){
        const int o0 = 16*mi + 4*hi;
#pragma unroll
        for (int ni = 0; ni < 4; ++ni){
            const int p = 16*ni + li;
            uint2 pk;
            pk.x = (unsigned)(unsigned short)hfc(acc[mi][ni][0]) | ((unsigned)(unsigned short)hfc(acc[mi][ni][1]) << 16);
            pk.y = (unsigned)(unsigned short)hfc(acc[mi][ni][2]) | ((unsigned)(unsigned short)hfc(acc[mi][ni][3]) << 16);
            *(uint2*)(Tt + ((p*64 + o0) ^ ((li & 7) << 3))) = pk;
        }
    }
}

// swizzled tile row l -> global (coalesced dwordx4 per 16B)
__device__ __forceinline__ void tstore(const short* __restrict__ Tt, short* __restrict__ gout, int l)
{
#pragma unroll
    for (int g = 0; g < 8; ++g){
        uint4 d = *(const uint4*)(Tt + ((l*64 + g*8) ^ ((l & 7) << 3)));
        *(uint4*)(gout + g*8) = d;
    }
}

// ---------------------------------------------------------------------------
// K1: full fused MFMA chain -> wgt (fp16, [b][r][c]) , val2 (fp16, [b][r][c])
// ONE wave per block, 16KB LDS -> 10 blocks/CU.
// __launch_bounds__(64,4): cap allocator at 128 VGPR (round-4 lesson: without
// the hint the compiler used 192 VGPR -> 2 waves/SIMD -> occupancy collapse).
// ---------------------------------------------------------------------------
__global__ void __launch_bounds__(64, 4) k1_kernel(
    const float* __restrict__ xyz, const float* __restrict__ feat,
    const short* __restrict__ wbf,
    const float* __restrict__ kb,  const float* __restrict__ vb,
    const float* __restrict__ pm1b, const float* __restrict__ pm2b,
    const float* __restrict__ pb1b, const float* __restrict__ pb2b,
    const float* __restrict__ we1b, const float* __restrict__ we2b,
    short* __restrict__ o_val2, short* __restrict__ o_wgt)
{
    __shared__ short Fs[4096];   // 8KB feature/temp tile
    __shared__ short Ts[4096];   // 8KB temp tile
    const int l = threadIdx.x;
    const int li = l & 15, hi = l >> 4;
    short* F = Fs;
    short* T = Ts;
    const int b = blockIdx.x >> 10;
    const int rbase = (blockIdx.x & 1023) << 6;

    // ---- stage feature tile: [p=l][c] bf16, swizzled ----
    {
        const float* fb = feat + (size_t)(b * 64) * NKr + rbase + l;
#pragma unroll 4
        for (int c0 = 0; c0 < 64; c0 += 8){
            short v[8];
#pragma unroll
            for (int j = 0; j < 8; ++j) v[j] = bfc(fb[(size_t)(c0 + j) * NKr]);
            uint4 pk;
            pk.x = (unsigned)(unsigned short)v[0] | ((unsigned)(unsigned short)v[1] << 16);
            pk.y = (unsigned)(unsigned short)v[2] | ((unsigned)(unsigned short)v[3] << 16);
            pk.z = (unsigned)(unsigned short)v[4] | ((unsigned)(unsigned short)v[5] << 16);
            pk.w = (unsigned)(unsigned short)v[6] | ((unsigned)(unsigned short)v[7] << 16);
            *(uint4*)(F + ((l*64 + c0) ^ ((l & 7) << 3))) = pk;
        }
    }
    // ---- xyz B-frags in regs (K padded 3->32; only hi==0 lanes non-zero) ----
    s16x8 xf[4];
#pragma unroll
    for (int ni = 0; ni < 4; ++ni)
#pragma unroll
        for (int j = 0; j < 8; ++j) xf[ni][j] = 0;
    if (hi == 0){
        const float* xb = xyz + (size_t)(b * 3) * NKr + rbase;
#pragma unroll
        for (int ni = 0; ni < 4; ++ni){
            const int p = 16*ni + li;
            xf[ni][0] = bfc(xb[p]);
            xf[ni][1] = bfc(xb[NKr + p]);
            xf[ni][2] = bfc(xb[2*NKr + p]);
        }
    }

    f32x4 A1[4][4], A2[4][4];
    // key = kW@f + kb
    gemm64(F, wbf, 12288, kb, li, hi, A1);
    // t1 = relu(pm1@xyz + pm1b) -> T
    gemm32x(xf, wbf, 0, pm1b, li, hi, A2);
    dstore_bf(T, A2, li, hi, true);
    // pem = pm2@t1 + pm2b
    gemm64(T, wbf, 4096, pm2b, li, hi, A2);
    // kp = key * pem
#pragma unroll
    for (int mi = 0; mi < 4; ++mi)
#pragma unroll
        for (int ni = 0; ni < 4; ++ni)
#pragma unroll
            for (int j = 0; j < 4; ++j) A1[mi][ni][j] *= A2[mi][ni][j];
    // t2 = relu(pb1@xyz + pb1b) -> T
    gemm32x(xf, wbf, 2048, pb1b, li, hi, A2);
    dstore_bf(T, A2, li, hi, true);
    // peb = pb2@t2 + pb2b   (stays live in A2)
    gemm64(T, wbf, 8192, pb2b, li, hi, A2);
    // rqk = kp + peb -> T
#pragma unroll
    for (int mi = 0; mi < 4; ++mi)
#pragma unroll
        for (int ni = 0; ni < 4; ++ni)
#pragma unroll
            for (int j = 0; j < 4; ++j) A1[mi][ni][j] += A2[mi][ni][j];
    dstore_bf(T, A1, li, hi, false);
    // value = vW@f + vb ; val2 = value + peb -> F (fp16) -> global
    gemm64(F, wbf, 16384, vb, li, hi, A1);
#pragma unroll
    for (int mi = 0; mi < 4; ++mi)
#pragma unroll
        for (int ni = 0; ni < 4; ++ni)
#pragma unroll
            for (int j = 0; j < 4; ++j) A1[mi][ni][j] += A2[mi][ni][j];
    dstore_h16(F, A1, li, hi);
    const size_t rowoff = ((size_t)b * NKr + rbase + l) * 64;
    tstore(F, o_val2 + rowoff, l);
    // t3 = relu(we1@rqk + we1b) -> F
    gemm64(T, wbf, 20480, we1b, li, hi, A1);
    dstore_bf(F, A1, li, hi, true);
    // wgt = we2@t3 + we2b -> T (fp16) -> global
    gemm64(F, wbf, 24576, we2b, li, hi, A1);
    dstore_h16(T, A1, li, hi);
    tstore(T, o_wgt + rowoff, l);
}

// ---------------------------------------------------------------------------
// K2: online softmax stats over n per (b,c,k). wgt is [b][n*16+k][c] fp16.
// grid = b(8) x k(16) x chalf(2) = 256 blocks, 512 thr.
// ---------------------------------------------------------------------------
__device__ __forceinline__ void comb(float& m, float& S, float mo, float So)
{
    float mn = fmaxf(m, mo);
    S = S * exp2f((m - mn) * LOG2E) + So * exp2f((mo - mn) * LOG2E);
    m = mn;
}

__global__ void __launch_bounds__(512) k2_kernel(const short* __restrict__ wgt,
                                                 float* __restrict__ mstat,
                                                 float* __restrict__ rstat)
{
    __shared__ float redm[8][4][8], reds[8][4][8];
    const int blk = blockIdx.x;
    const int b = blk >> 5, k = (blk >> 1) & 15, h = blk & 1;
    const int t = threadIdx.x;
    const int oct = t & 3, g = t >> 2;            // c0 = h*32+oct*8 ; row group g (0..127)
    const short* wp = wgt + (size_t)b * NKr * 64 + (size_t)k * 64 + h * 32 + oct * 8;

    float m[8], S[8];
#pragma unroll
    for (int j = 0; j < 8; ++j){ m[j] = -3.0e38f; S[j] = 0.f; }
#pragma unroll 2
    for (int i = 0; i < 32; ++i){
        const int n = g + 128 * i;
        const uint4 u = *(const uint4*)(wp + (size_t)n * 1024);
        unsigned short hs[8] = {
            (unsigned short)(u.x & 0xffffu), (unsigned short)(u.x >> 16),
            (unsigned short)(u.y & 0xffffu), (unsigned short)(u.y >> 16),
            (unsigned short)(u.z & 0xffffu), (unsigned short)(u.z >> 16),
            (unsigned short)(u.w & 0xffffu), (unsigned short)(u.w >> 16)};
#pragma unroll
        for (int j = 0; j < 8; ++j){
            const float x = hdec(hs[j]);
            const float mn = fmaxf(m[j], x);
            S[j] = S[j] * exp2f((m[j] - mn) * LOG2E) + exp2f((x - mn) * LOG2E);
            m[j] = mn;
        }
    }
    // in-wave reduce across g-low (xor 4,8,16,32)
#pragma unroll
    for (int d = 4; d <= 32; d <<= 1){
#pragma unroll
        for (int j = 0; j < 8; ++j){
            float mo = __shfl_xor(m[j], d, 64);
            float So = __shfl_xor(S[j], d, 64);
            comb(m[j], S[j], mo, So);
        }
    }
    const int wv = t >> 6, ln = t & 63;
    if (ln < 4){
#pragma unroll
        for (int j = 0; j < 8; ++j){ redm[wv][ln][j] = m[j]; reds[wv][ln][j] = S[j]; }
    }
    __syncthreads();
    if (t < 32){
        const int oc = t >> 3, j = t & 7;
        float M = redm[0][oc][j], Sm = reds[0][oc][j];
#pragma unroll
        for (int wv2 = 1; wv2 < 8; ++wv2) comb(M, Sm, redm[wv2][oc][j], reds[wv2][oc][j]);
        const int idx = (b * 16 + k) * 64 + h * 32 + oc * 8 + j;
        mstat[idx] = M;
        rstat[idx] = 1.0f / Sm;
    }
}

// ---------------------------------------------------------------------------
// K3: score = exp(w-m)*rs ; feature = relu(score*val2) -> MFMA resW -> out
// ONE wave per block, 16KB LDS, VGPR capped via launch_bounds(64,4).
// ---------------------------------------------------------------------------
__global__ void __launch_bounds__(64, 4) k3_kernel(
    const short* __restrict__ wgt, const short* __restrict__ val2,
    const float* __restrict__ mstat, const float* __restrict__ rstat,
    const short* __restrict__ wbf, const float* __restrict__ resb,
    float* __restrict__ out)
{
    __shared__ short ftile[4096];
    __shared__ float mls[1024], rls[1024];      // [k][c] fp32, swizzled f^=((k&7)<<2)
    const int l = threadIdx.x;
    const int li = l & 15, hi = l >> 4;
    const int b = blockIdx.x >> 10;
    const int rbase = (blockIdx.x & 1023) << 6;

    {
        const float* mp = mstat + b * 1024;
        const float* rp = rstat + b * 1024;
#pragma unroll
        for (int i = 0; i < 16; ++i){
            const int f = l + 64 * i;
            const int kk = f >> 6;                 // == i
            const int fs = f ^ ((kk & 7) << 2);
            mls[fs] = mp[f];
            rls[fs] = rp[f];
        }
    }
    __syncthreads();

    short* Ft = ftile;
    const int k = l & 15;                        // rbase % 64 == 0
    const size_t rowoff = ((size_t)b * NKr + rbase + l) * 64;
    const short* wp = wgt + rowoff;
    const short* vp = val2 + rowoff;
#pragma unroll 2
    for (int g = 0; g < 8; ++g){
        const uint4 uw = *(const uint4*)(wp + g * 8);
        const uint4 uv = *(const uint4*)(vp + g * 8);
        const int f0 = (k * 64 + g * 8) ^ ((k & 7) << 2);
        const int f1 = (k * 64 + g * 8 + 4) ^ ((k & 7) << 2);
        const float4 m0 = *(const float4*)(mls + f0);
        const float4 m1 = *(const float4*)(mls + f1);
        const float4 r0 = *(const float4*)(rls + f0);
        const float4 r1 = *(const float4*)(rls + f1);
        const unsigned short ws8[8] = {
            (unsigned short)(uw.x & 0xffffu), (unsigned short)(uw.x >> 16),
            (unsigned short)(uw.y & 0xffffu), (unsigned short)(uw.y >> 16),
            (unsigned short)(uw.z & 0xffffu), (unsigned short)(uw.z >> 16),
            (unsigned short)(uw.w & 0xffffu), (unsigned short)(uw.w >> 16)};
        const unsigned short vs8[8] = {
            (unsigned short)(uv.x & 0xffffu), (unsigned short)(uv.x >> 16),
            (unsigned short)(uv.y & 0xffffu), (unsigned short)(uv.y >> 16),
            (unsigned short)(uv.z & 0xffffu), (unsigned short)(uv.z >> 16),
            (unsigned short)(uv.w & 0xffffu), (unsigned short)(uv.w >> 16)};
        const float mv[8] = {m0.x, m0.y, m0.z, m0.w, m1.x, m1.y, m1.z, m1.w};
        const float rv[8] = {r0.x, r0.y, r0.z, r0.w, r1.x, r1.y, r1.z, r1.w};
        short fo[8];
#pragma unroll
        for (int j = 0; j < 8; ++j){
            const float sc = exp2f((hdec(ws8[j]) - mv[j]) * LOG2E) * rv[j];
            fo[j] = bfc(fmaxf(sc * hdec(vs8[j]), 0.f));
        }
        uint4 pk;
        pk.x = (unsigned)(unsigned short)fo[0] | ((unsigned)(unsigned short)fo[1] << 16);
        pk.y = (unsigned)(unsigned short)fo[2] | ((unsigned)(unsigned short)fo[3] << 16);
        pk.z = (unsigned)(unsigned short)fo[4] | ((unsigned)(unsigned short)fo[5] << 16);
        pk.w = (unsigned)(unsigned short)fo[6] | ((unsigned)(unsigned short)fo[7] << 16);
        *(uint4*)(Ft + ((l * 64 + g * 8) ^ ((l & 7) << 3))) = pk;
    }
    // out = resW @ feature + resb
    f32x4 acc[4][4];
    gemm64(Ft, wbf, 28672, resb, li, hi, acc);
    float* op = out + (size_t)b * 64 * NKr;
#pragma unroll
    for (int mi = 0; mi < 4; ++mi){
        const int o0 = 16 * mi + 4 * hi;
#pragma unroll
        for (int ni = 0; ni < 4; ++ni){
            const int r = rbase + 16 * ni + li;
#pragma unroll
            for (int j = 0; j < 4; ++j)
                op[(size_t)(o0 + j) * NKr + r] = acc[mi][ni][j];
        }
    }
}

// ---------------------------------------------------------------------------
extern "C" void kernel_launch(void* const* d_in, const int* in_sizes, int n_in,
                              void* d_out, int out_size, void* d_ws, size_t ws_size,
                              hipStream_t stream)
{
    const float* xyz  = (const float*)d_in[0];
    const float* feat = (const float*)d_in[1];
    const float* kW   = (const float*)d_in[2];  const float* kb   = (const float*)d_in[3];
    const float* vW   = (const float*)d_in[4];  const float* vb   = (const float*)d_in[5];
    const float* pm1W = (const float*)d_in[6];  const float* pm1b = (const float*)d_in[7];
    const float* pm2W = (const float*)d_in[8];  const float* pm2b = (const float*)d_in[9];
    const float* pb1W = (const float*)d_in[10]; const float* pb1b = (const float*)d_in[11];
    const float* pb2W = (const float*)d_in[12]; const float* pb2b = (const float*)d_in[13];
    const float* we1W = (const float*)d_in[14]; const float* we1b = (const float*)d_in[15];
    const float* we2W = (const float*)d_in[16]; const float* we2b = (const float*)d_in[17];
    const float* resW = (const float*)d_in[18]; const float* resb = (const float*)d_in[19];

    short* wbf   = (short*)d_ws;                              // 65536 B
    float* mstat = (float*)((char*)d_ws + 65536);             // 32768 B
    float* rstat = (float*)((char*)d_ws + 98304);             // 32768 B
    short* val2  = (short*)((char*)d_ws + 131072);            // 64 MB
    short* wgt   = (short*)((char*)d_ws + 131072 + 67108864); // 64 MB

    k0_kernel<<<64, 256, 0, stream>>>(pm1W, pb1W, pm2W, pb2W, kW, vW, we1W, we2W, resW, wbf);
    k1_kernel<<<8192, 64, 0, stream>>>(xyz, feat, wbf, kb, vb, pm1b, pm2b,
                                       pb1b, pb2b, we1b, we2b, val2, wgt);
    k2_kernel<<<256, 512, 0, stream>>>(wgt, mstat, rstat);
    k3_kernel<<<8192, 64, 0, stream>>>(wgt, val2, mstat, rstat, wbf, resb, (float*)d_out);
}

// Round 9
// 380.552 us; speedup vs baseline: 1.1508x; 1.1508x over previous
//
#include <hip/hip_runtime.h>
#include <hip/hip_fp16.h>

#define NKr 65536   // N*K positions per batch
#define LOG2E 1.44269504f

typedef __attribute__((ext_vector_type(4))) float f32x4;
typedef __attribute__((ext_vector_type(8))) short s16x8;

// fp32 -> bf16 (RNE)
__device__ __forceinline__ short bfc(float x){
    union{float f; unsigned u;} a; a.f = x;
    unsigned r = a.u + 0x7fffu + ((a.u >> 16) & 1u);
    return (short)(r >> 16);
}
__device__ __forceinline__ short hfc(float x){
    __half h = __float2half(x);
    return *(short*)&h;
}
__device__ __forceinline__ float hdec(unsigned short s){
    __half h = *(__half*)&s;
    return __half2float(h);
}

// ---------------------------------------------------------------------------
// K0: weights -> bf16. wbf (halves): pm1p@0 [64][32] zero-pad, pb1p@2048,
// 64x64: pm2@4096, pb2@8192, kW@12288, vW@16384, we1@20480, we2@24576, resW@28672.
// ---------------------------------------------------------------------------
__global__ void k0_kernel(const float* __restrict__ pm1W, const float* __restrict__ pb1W,
                          const float* __restrict__ pm2W, const float* __restrict__ pb2W,
                          const float* __restrict__ kW,   const float* __restrict__ vW,
                          const float* __restrict__ we1W, const float* __restrict__ we2W,
                          const float* __restrict__ resW, short* __restrict__ wbf)
{
    const int tg = blockIdx.x * 256 + threadIdx.x;
    for (int i = tg; i < 32768; i += 16384){
        short v;
        if (i < 2048){
            const int o = i >> 5, c = i & 31;
            v = (c < 3) ? bfc(pm1W[o*3 + c]) : (short)0;
        } else if (i < 4096){
            const int ii = i - 2048, o = ii >> 5, c = ii & 31;
            v = (c < 3) ? bfc(pb1W[o*3 + c]) : (short)0;
        } else {
            const int m = (i - 4096) >> 12, j = (i - 4096) & 4095;
            const float* s = (m == 0) ? pm2W : (m == 1) ? pb2W : (m == 2) ? kW
                           : (m == 3) ? vW   : (m == 4) ? we1W : (m == 5) ? we2W : resW;
            v = bfc(s[j]);
        }
        wbf[i] = v;
    }
}

// ---------------------------------------------------------------------------
// Slice-GEMM helpers. Wave w owns output rows [16w,16w+16). Tile: [p][64c],
// half_idx swizzle ^((p&7)<<3). MFMA 16x16x32 bf16 mapping:
// A lane: m=li, k=hi*8+j ; B lane: k=hi*8+j, n=li ; D lane: o=4hi+j, p=16ni+li.
// Per-wave acc = 4 x f32x4 (16 regs) -> 3 live value-sets fit under 128 VGPR.
// ---------------------------------------------------------------------------
__device__ __forceinline__ void sgemm64(const short* __restrict__ S,
                                        const short* __restrict__ wbf, int wo,
                                        const float* __restrict__ bias,
                                        int w, int li, int hi, f32x4 acc[4])
{
    const float4 bv = *(const float4*)(bias + 16*w + 4*hi);
#pragma unroll
    for (int ni = 0; ni < 4; ++ni){
        acc[ni][0] = bv.x; acc[ni][1] = bv.y; acc[ni][2] = bv.z; acc[ni][3] = bv.w;
    }
#pragma unroll
    for (int ks = 0; ks < 2; ++ks){
        const s16x8 af = *(const s16x8*)(wbf + wo + (16*w + li)*64 + ks*32 + hi*8);
#pragma unroll
        for (int ni = 0; ni < 4; ++ni){
            const s16x8 bf_ = *(const s16x8*)(S + (((16*ni + li)*64 + ks*32 + hi*8) ^ ((li & 7) << 3)));
            acc[ni] = __builtin_amdgcn_mfma_f32_16x16x32_bf16(af, bf_, acc[ni], 0, 0, 0);
        }
    }
}

__device__ __forceinline__ void sgemm32x(const s16x8* __restrict__ xf,
                                         const short* __restrict__ wbf, int wo,
                                         const float* __restrict__ bias,
                                         int w, int li, int hi, f32x4 acc[4])
{
    const float4 bv = *(const float4*)(bias + 16*w + 4*hi);
#pragma unroll
    for (int ni = 0; ni < 4; ++ni){
        acc[ni][0] = bv.x; acc[ni][1] = bv.y; acc[ni][2] = bv.z; acc[ni][3] = bv.w;
    }
    const s16x8 af = *(const s16x8*)(wbf + wo + (16*w + li)*32 + hi*8);
#pragma unroll
    for (int ni = 0; ni < 4; ++ni)
        acc[ni] = __builtin_amdgcn_mfma_f32_16x16x32_bf16(af, xf[ni], acc[ni], 0, 0, 0);
}

__device__ __forceinline__ void sdstore_bf(short* __restrict__ T, const f32x4 acc[4],
                                           int w, int li, int hi, bool relu)
{
    const int o0 = 16*w + 4*hi;
#pragma unroll
    for (int ni = 0; ni < 4; ++ni){
        float a0 = acc[ni][0], a1 = acc[ni][1], a2 = acc[ni][2], a3 = acc[ni][3];
        if (relu){ a0 = fmaxf(a0,0.f); a1 = fmaxf(a1,0.f); a2 = fmaxf(a2,0.f); a3 = fmaxf(a3,0.f); }
        uint2 pk;
        pk.x = (unsigned)(unsigned short)bfc(a0) | ((unsigned)(unsigned short)bfc(a1) << 16);
        pk.y = (unsigned)(unsigned short)bfc(a2) | ((unsigned)(unsigned short)bfc(a3) << 16);
        *(uint2*)(T + (((16*ni + li)*64 + o0) ^ ((li & 7) << 3))) = pk;
    }
}

__device__ __forceinline__ void sdstore_h16(short* __restrict__ T, const f32x4 acc[4],
                                            int w, int li, int hi)
{
    const int o0 = 16*w + 4*hi;
#pragma unroll
    for (int ni = 0; ni < 4; ++ni){
        uint2 pk;
        pk.x = (unsigned)(unsigned short)hfc(acc[ni][0]) | ((unsigned)(unsigned short)hfc(acc[ni][1]) << 16);
        pk.y = (unsigned)(unsigned short)hfc(acc[ni][2]) | ((unsigned)(unsigned short)hfc(acc[ni][3]) << 16);
        *(uint2*)(T + (((16*ni + li)*64 + o0) ^ ((li & 7) << 3))) = pk;
    }
}

// ---------------------------------------------------------------------------
// K1: fused chain, 4-wave blocks, waves slice output channels (16 each).
// Shared tiles F/T/Vt (8KB each = 24KB) -> (256,4) feasible: 4 blk/CU x 24KB
// = 96KB LDS, VGPR cap 128. (r4/r5 lesson: infeasible waves/EU requests are
// silently dropped -> 192 VGPR; keep the resource vector feasible.)
// ---------------------------------------------------------------------------
__global__ void __launch_bounds__(256, 4) k1_kernel(
    const float* __restrict__ xyz, const float* __restrict__ feat,
    const short* __restrict__ wbf,
    const float* __restrict__ kb,  const float* __restrict__ vb,
    const float* __restrict__ pm1b, const float* __restrict__ pm2b,
    const float* __restrict__ pb1b, const float* __restrict__ pb2b,
    const float* __restrict__ we1b, const float* __restrict__ we2b,
    short* __restrict__ o_val2, short* __restrict__ o_wgt)
{
    __shared__ short F[4096];    // feature, later t3
    __shared__ short T[4096];    // t1 / t2 / rqk
    __shared__ short Vt[4096];   // val2 / wgt staging (fp16)
    const int tid = threadIdx.x;
    const int w = tid >> 6, l = tid & 63;
    const int li = l & 15, hi = l >> 4;
    const int b = blockIdx.x >> 10;
    const int rbase = (blockIdx.x & 1023) << 6;

    // ---- stage F: thread = (pos l, channel chunk 16w..16w+16), coalesced 256B/instr
    {
        const float* fb = feat + ((size_t)(b*64 + 16*w)) * NKr + rbase + l;
        short v[16];
#pragma unroll
        for (int j = 0; j < 16; ++j) v[j] = bfc(fb[(size_t)j * NKr]);
        uint4 p0, p1;
        p0.x = (unsigned)(unsigned short)v[0] | ((unsigned)(unsigned short)v[1] << 16);
        p0.y = (unsigned)(unsigned short)v[2] | ((unsigned)(unsigned short)v[3] << 16);
        p0.z = (unsigned)(unsigned short)v[4] | ((unsigned)(unsigned short)v[5] << 16);
        p0.w = (unsigned)(unsigned short)v[6] | ((unsigned)(unsigned short)v[7] << 16);
        p1.x = (unsigned)(unsigned short)v[8] | ((unsigned)(unsigned short)v[9] << 16);
        p1.y = (unsigned)(unsigned short)v[10] | ((unsigned)(unsigned short)v[11] << 16);
        p1.z = (unsigned)(unsigned short)v[12] | ((unsigned)(unsigned short)v[13] << 16);
        p1.w = (unsigned)(unsigned short)v[14] | ((unsigned)(unsigned short)v[15] << 16);
        const int s0 = l*64 + 16*w;
        *(uint4*)(F + (s0 ^ ((l & 7) << 3))) = p0;
        *(uint4*)(F + ((s0 + 8) ^ ((l & 7) << 3))) = p1;
    }
    // ---- xyz B-frags (K padded 3->32; only hi==0, j<3 nonzero)
    s16x8 xf[4];
#pragma unroll
    for (int ni = 0; ni < 4; ++ni)
#pragma unroll
        for (int j = 0; j < 8; ++j) xf[ni][j] = 0;
    if (hi == 0){
        const float* xb = xyz + (size_t)(b*3) * NKr + rbase;
#pragma unroll
        for (int ni = 0; ni < 4; ++ni){
            xf[ni][0] = bfc(xb[16*ni + li]);
            xf[ni][1] = bfc(xb[NKr + 16*ni + li]);
            xf[ni][2] = bfc(xb[2*NKr + 16*ni + li]);
        }
    }
    __syncthreads();                                   // B1: F ready

    f32x4 V[4], K[4], P[4];
    sgemm64(F, wbf, 16384, vb, w, li, hi, V);          // value (f32, stays live)
    sgemm64(F, wbf, 12288, kb, w, li, hi, K);          // key   (f32, stays live)
    sgemm32x(xf, wbf, 0, pm1b, w, li, hi, P);          // t1
    sdstore_bf(T, P, w, li, hi, true);
    __syncthreads();                                   // B2: t1 ready
    sgemm64(T, wbf, 4096, pm2b, w, li, hi, P);         // pem
#pragma unroll
    for (int ni = 0; ni < 4; ++ni)
#pragma unroll
        for (int j = 0; j < 4; ++j) K[ni][j] *= P[ni][j];   // kp
    __syncthreads();                                   // B3: t1 reads done
    sgemm32x(xf, wbf, 2048, pb1b, w, li, hi, P);       // t2
    sdstore_bf(T, P, w, li, hi, true);
    __syncthreads();                                   // B4: t2 ready
    sgemm64(T, wbf, 8192, pb2b, w, li, hi, P);         // peb (stays in P)
    __syncthreads();                                   // B5: t2 reads done
    {   // rqk = kp + peb -> T ; val2 = value + peb -> Vt
        f32x4 R[4];
#pragma unroll
        for (int ni = 0; ni < 4; ++ni)
#pragma unroll
            for (int j = 0; j < 4; ++j) R[ni][j] = K[ni][j] + P[ni][j];
        sdstore_bf(T, R, w, li, hi, false);
#pragma unroll
        for (int ni = 0; ni < 4; ++ni)
#pragma unroll
            for (int j = 0; j < 4; ++j) R[ni][j] = V[ni][j] + P[ni][j];
        sdstore_h16(Vt, R, w, li, hi);
    }
    __syncthreads();                                   // B6: rqk + val2 ready
    {   // coop tstore val2 (thread = row p, 32B chunk sub)
        const int p = tid >> 2, sub = tid & 3;
        const int s0 = p*64 + sub*16;
        const uint4 d0 = *(const uint4*)(Vt + (s0 ^ ((p & 7) << 3)));
        const uint4 d1 = *(const uint4*)(Vt + ((s0 + 8) ^ ((p & 7) << 3)));
        short* gp = o_val2 + ((size_t)b * NKr + rbase + p) * 64 + sub*16;
        *(uint4*)gp = d0;
        *(uint4*)(gp + 8) = d1;
    }
    sgemm64(T, wbf, 20480, we1b, w, li, hi, P);        // t3 = relu(we1@rqk)
    sdstore_bf(F, P, w, li, hi, true);                 // F reusable (feature dead)
    __syncthreads();                                   // B7: t3 ready, val2 tstore done
    sgemm64(F, wbf, 24576, we2b, w, li, hi, P);        // wgt
    sdstore_h16(Vt, P, w, li, hi);
    __syncthreads();                                   // B8: wgt staged
    {   // coop tstore wgt
        const int p = tid >> 2, sub = tid & 3;
        const int s0 = p*64 + sub*16;
        const uint4 d0 = *(const uint4*)(Vt + (s0 ^ ((p & 7) << 3)));
        const uint4 d1 = *(const uint4*)(Vt + ((s0 + 8) ^ ((p & 7) << 3)));
        short* gp = o_wgt + ((size_t)b * NKr + rbase + p) * 64 + sub*16;
        *(uint4*)gp = d0;
        *(uint4*)(gp + 8) = d1;
    }
}

// ---------------------------------------------------------------------------
// K2: online softmax stats over n per (b,c,k). wgt is [b][n*16+k][c] fp16.
// grid = b(8) x k(16) x chalf(2) = 256 blocks, 512 thr.
// ---------------------------------------------------------------------------
__device__ __forceinline__ void comb(float& m, float& S, float mo, float So)
{
    float mn = fmaxf(m, mo);
    S = S * exp2f((m - mn) * LOG2E) + So * exp2f((mo - mn) * LOG2E);
    m = mn;
}

__global__ void __launch_bounds__(512) k2_kernel(const short* __restrict__ wgt,
                                                 float* __restrict__ mstat,
                                                 float* __restrict__ rstat)
{
    __shared__ float redm[8][4][8], reds[8][4][8];
    const int blk = blockIdx.x;
    const int b = blk >> 5, k = (blk >> 1) & 15, h = blk & 1;
    const int t = threadIdx.x;
    const int oct = t & 3, g = t >> 2;
    const short* wp = wgt + (size_t)b * NKr * 64 + (size_t)k * 64 + h * 32 + oct * 8;

    float m[8], S[8];
#pragma unroll
    for (int j = 0; j < 8; ++j){ m[j] = -3.0e38f; S[j] = 0.f; }
#pragma unroll 2
    for (int i = 0; i < 32; ++i){
        const int n = g + 128 * i;
        const uint4 u = *(const uint4*)(wp + (size_t)n * 1024);
        unsigned short hs[8] = {
            (unsigned short)(u.x & 0xffffu), (unsigned short)(u.x >> 16),
            (unsigned short)(u.y & 0xffffu), (unsigned short)(u.y >> 16),
            (unsigned short)(u.z & 0xffffu), (unsigned short)(u.z >> 16),
            (unsigned short)(u.w & 0xffffu), (unsigned short)(u.w >> 16)};
#pragma unroll
        for (int j = 0; j < 8; ++j){
            const float x = hdec(hs[j]);
            const float mn = fmaxf(m[j], x);
            S[j] = S[j] * exp2f((m[j] - mn) * LOG2E) + exp2f((x - mn) * LOG2E);
            m[j] = mn;
        }
    }
#pragma unroll
    for (int d = 4; d <= 32; d <<= 1){
#pragma unroll
        for (int j = 0; j < 8; ++j){
            float mo = __shfl_xor(m[j], d, 64);
            float So = __shfl_xor(S[j], d, 64);
            comb(m[j], S[j], mo, So);
        }
    }
    const int wv = t >> 6, ln = t & 63;
    if (ln < 4){
#pragma unroll
        for (int j = 0; j < 8; ++j){ redm[wv][ln][j] = m[j]; reds[wv][ln][j] = S[j]; }
    }
    __syncthreads();
    if (t < 32){
        const int oc = t >> 3, j = t & 7;
        float M = redm[0][oc][j], Sm = reds[0][oc][j];
#pragma unroll
        for (int wv2 = 1; wv2 < 8; ++wv2) comb(M, Sm, redm[wv2][oc][j], reds[wv2][oc][j]);
        const int idx = (b * 16 + k) * 64 + h * 32 + oc * 8 + j;
        mstat[idx] = M;
        rstat[idx] = 1.0f / Sm;
    }
}

// ---------------------------------------------------------------------------
// K3: score = exp(w-m)*rs ; feature = relu(score*val2) -> slice-GEMM resW.
// 4-wave blocks, 8KB LDS; stats read from global (L2-resident, no staging).
// ---------------------------------------------------------------------------
__global__ void __launch_bounds__(256, 4) k3_kernel(
    const short* __restrict__ wgt, const short* __restrict__ val2,
    const float* __restrict__ mstat, const float* __restrict__ rstat,
    const short* __restrict__ wbf, const float* __restrict__ resb,
    float* __restrict__ out)
{
    __shared__ short F[4096];
    const int tid = threadIdx.x;
    const int b = blockIdx.x >> 10;
    const int rbase = (blockIdx.x & 1023) << 6;

    {   // stage: thread = (row p, 32B chunk sub); 4 lanes cover 128B line
        const int p = tid >> 2, sub = tid & 3;
        const int k = p & 15;
        const size_t ro = ((size_t)b * NKr + rbase + p) * 64 + sub*16;
        const uint4 uw0 = *(const uint4*)(wgt + ro);
        const uint4 uw1 = *(const uint4*)(wgt + ro + 8);
        const uint4 uv0 = *(const uint4*)(val2 + ro);
        const uint4 uv1 = *(const uint4*)(val2 + ro + 8);
        const float* mp = mstat + (b*16 + k)*64 + sub*16;
        const float* rp = rstat + (b*16 + k)*64 + sub*16;
        float mv[16], rv[16];
#pragma unroll
        for (int q = 0; q < 4; ++q){
            const float4 mq = *(const float4*)(mp + 4*q);
            const float4 rq = *(const float4*)(rp + 4*q);
            mv[4*q] = mq.x; mv[4*q+1] = mq.y; mv[4*q+2] = mq.z; mv[4*q+3] = mq.w;
            rv[4*q] = rq.x; rv[4*q+1] = rq.y; rv[4*q+2] = rq.z; rv[4*q+3] = rq.w;
        }
        const unsigned uu[8] = {uw0.x, uw0.y, uw0.z, uw0.w, uw1.x, uw1.y, uw1.z, uw1.w};
        const unsigned vv[8] = {uv0.x, uv0.y, uv0.z, uv0.w, uv1.x, uv1.y, uv1.z, uv1.w};
        short fo[16];
#pragma unroll
        for (int e = 0; e < 8; ++e){
            const float w0 = hdec((unsigned short)(uu[e] & 0xffffu));
            const float w1 = hdec((unsigned short)(uu[e] >> 16));
            const float v0 = hdec((unsigned short)(vv[e] & 0xffffu));
            const float v1 = hdec((unsigned short)(vv[e] >> 16));
            const float s0 = exp2f((w0 - mv[2*e]) * LOG2E) * rv[2*e];
            const float s1 = exp2f((w1 - mv[2*e+1]) * LOG2E) * rv[2*e+1];
            fo[2*e]   = bfc(fmaxf(s0 * v0, 0.f));
            fo[2*e+1] = bfc(fmaxf(s1 * v1, 0.f));
        }
        uint4 p0, p1;
        p0.x = (unsigned)(unsigned short)fo[0] | ((unsigned)(unsigned short)fo[1] << 16);
        p0.y = (unsigned)(unsigned short)fo[2] | ((unsigned)(unsigned short)fo[3] << 16);
        p0.z = (unsigned)(unsigned short)fo[4] | ((unsigned)(unsigned short)fo[5] << 16);
        p0.w = (unsigned)(unsigned short)fo[6] | ((unsigned)(unsigned short)fo[7] << 16);
        p1.x = (unsigned)(unsigned short)fo[8] | ((unsigned)(unsigned short)fo[9] << 16);
        p1.y = (unsigned)(unsigned short)fo[10] | ((unsigned)(unsigned short)fo[11] << 16);
        p1.z = (unsigned)(unsigned short)fo[12] | ((unsigned)(unsigned short)fo[13] << 16);
        p1.w = (unsigned)(unsigned short)fo[14] | ((unsigned)(unsigned short)fo[15] << 16);
        const int s0i = p*64 + sub*16;
        *(uint4*)(F + (s0i ^ ((p & 7) << 3))) = p0;
        *(uint4*)(F + ((s0i + 8) ^ ((p & 7) << 3))) = p1;
    }
    __syncthreads();

    const int w = tid >> 6, l = tid & 63;
    const int li = l & 15, hi = l >> 4;
    f32x4 acc[4];
    sgemm64(F, wbf, 28672, resb, w, li, hi, acc);
    float* op = out + (size_t)b * 64 * NKr;
#pragma unroll
    for (int ni = 0; ni < 4; ++ni){
        const int r = rbase + 16*ni + li;
#pragma unroll
        for (int j = 0; j < 4; ++j)
            op[(size_t)(16*w + 4*hi + j) * NKr + r] = acc[ni][j];
    }
}

// ---------------------------------------------------------------------------
extern "C" void kernel_launch(void* const* d_in, const int* in_sizes, int n_in,
                              void* d_out, int out_size, void* d_ws, size_t ws_size,
                              hipStream_t stream)
{
    const float* xyz  = (const float*)d_in[0];
    const float* feat = (const float*)d_in[1];
    const float* kW   = (const float*)d_in[2];  const float* kb   = (const float*)d_in[3];
    const float* vW   = (const float*)d_in[4];  const float* vb   = (const float*)d_in[5];
    const float* pm1W = (const float*)d_in[6];  const float* pm1b = (const float*)d_in[7];
    const float* pm2W = (const float*)d_in[8];  const float* pm2b = (const float*)d_in[9];
    const float* pb1W = (const float*)d_in[10]; const float* pb1b = (const float*)d_in[11];
    const float* pb2W = (const float*)d_in[12]; const float* pb2b = (const float*)d_in[13];
    const float* we1W = (const float*)d_in[14]; const float* we1b = (const float*)d_in[15];
    const float* we2W = (const float*)d_in[16]; const float* we2b = (const float*)d_in[17];
    const float* resW = (const float*)d_in[18]; const float* resb = (const float*)d_in[19];

    short* wbf   = (short*)d_ws;                              // 65536 B
    float* mstat = (float*)((char*)d_ws + 65536);             // 32768 B
    float* rstat = (float*)((char*)d_ws + 98304);             // 32768 B
    short* val2  = (short*)((char*)d_ws + 131072);            // 64 MB
    short* wgt   = (short*)((char*)d_ws + 131072 + 67108864); // 64 MB

    k0_kernel<<<64, 256, 0, stream>>>(pm1W, pb1W, pm2W, pb2W, kW, vW, we1W, we2W, resW, wbf);
    k1_kernel<<<8192, 256, 0, stream>>>(xyz, feat, wbf, kb, vb, pm1b, pm2b,
                                        pb1b, pb2b, we1b, we2b, val2, wgt);
    k2_kernel<<<256, 512, 0, stream>>>(wgt, mstat, rstat);
    k3_kernel<<<8192, 256, 0, stream>>>(wgt, val2, mstat, rstat, wbf, resb, (float*)d_out);
}